// Round 17
// baseline (166.495 us; speedup 1.0000x reference)
//
#include <hip/hip_runtime.h>
#include <hip/hip_bf16.h>
#include <stdint.h>

typedef unsigned int u32;
typedef unsigned short u16;
typedef __attribute__((ext_vector_type(8))) short bf16x8;   // 8 bf16 = 4 VGPRs
typedef __attribute__((ext_vector_type(4))) float f32x4;

#define MFMA(a, b, c) __builtin_amdgcn_mfma_f32_16x16x32_bf16(a, b, c, 0, 0, 0)

__device__ __forceinline__ u16 f2bf(float f) {            // RNE float->bf16
  u32 u = __float_as_uint(f);
  return (u16)((u + 0x7FFFu + ((u >> 16) & 1u)) >> 16);
}
__device__ __forceinline__ float bf2f(u16 h) {
  return __uint_as_float(((u32)h) << 16);
}
// rational sigmoid via v_rcp (1 trans op instead of ~10-op exact-div sequence)
__device__ __forceinline__ float rsig_fast(float sc) {
  return 0.5f + 0.5f * sc * __builtin_amdgcn_rcpf(fabsf(sc) + 1.f);
}
// async global->LDS, 16B per lane. LDS dest is wave-uniform base + lane*16 (linear).
__device__ __forceinline__ void async16(void* lds, const void* g) {
  __builtin_amdgcn_global_load_lds((const __attribute__((address_space(1))) u32*)g,
                                   (__attribute__((address_space(3))) u32*)lds, 16, 0, 0);
}

// ---------------- fp32 -> bf16 weight conversion, all 4 weights in one launch -----
__global__ __launch_bounds__(256) void to_bf16_all(const float* __restrict__ s0, u16* __restrict__ d0,
                                                   const float* __restrict__ s1, u16* __restrict__ d1,
                                                   const float* __restrict__ s2, u16* __restrict__ d2,
                                                   const float* __restrict__ s3, u16* __restrict__ d3) {
  int b = blockIdx.x;                        // segs: 1536 | 512 | 4096 | 2048 blocks
  const float* src; u16* dst;
  if (b < 1536)      { src = s0; dst = d0; }
  else if (b < 2048) { src = s1; dst = d1; b -= 1536; }
  else if (b < 6144) { src = s2; dst = d2; b -= 2048; }
  else               { src = s3; dst = d3; b -= 6144; }
  const size_t i = (size_t)b * 256 + threadIdx.x;
  const float4 a = ((const float4*)src)[2 * i];
  const float4 c = ((const float4*)src)[2 * i + 1];
  ushort4 o0, o1;
  o0.x = f2bf(a.x); o0.y = f2bf(a.y); o0.z = f2bf(a.z); o0.w = f2bf(a.w);
  o1.x = f2bf(c.x); o1.y = f2bf(c.y); o1.z = f2bf(c.z); o1.w = f2bf(c.w);
  ((ushort4*)dst)[2 * i] = o0;
  ((ushort4*)dst)[2 * i + 1] = o1;
}

// ---------------- mr_norm: x / (mean|x| + eps) * w  -> bf16, one block per row ----
__global__ __launch_bounds__(256) void mrnorm(const float* __restrict__ x,
                                              const float* __restrict__ wg,
                                              u16* __restrict__ out) {
  const int row = blockIdx.x;
  const int tid = threadIdx.x;
  const float4 v = ((const float4*)(x + (size_t)row * 1024))[tid];
  float s = fabsf(v.x) + fabsf(v.y) + fabsf(v.z) + fabsf(v.w);
#pragma unroll
  for (int off = 1; off < 64; off <<= 1) s += __shfl_xor(s, off);
  __shared__ float red[4];
  if ((tid & 63) == 0) red[tid >> 6] = s;
  __syncthreads();
  const float inv = 1.f / ((red[0] + red[1] + red[2] + red[3]) * (1.f / 1024.f) + 1e-6f);
  const float4 g = ((const float4*)wg)[tid];
  ushort4 o;
  o.x = f2bf(v.x * inv * g.x);
  o.y = f2bf(v.y * inv * g.y);
  o.z = f2bf(v.z * inv * g.z);
  o.w = f2bf(v.w * inv * g.w);
  ((ushort4*)out)[(size_t)row * 256 + tid] = o;
}

// ---------------- GEMM: C[M][N] = A[M][K] @ B[N][K]^T  (bf16 in, fp32 acc) --------
// 128x128 tile, BK=64, 256 thr = 4 waves (2x2), each wave 64x64 via 4x4 16x16x32 MFMA.
// LDS staged by global_load_lds (linear dest) with XOR-swizzled SOURCE column;
// ds_read_b128 applies the same XOR -> bank-conflict-free (T2 / G21).
// DBUF=true: 2-phase double-buffer (stage next tile before computing current, one
// barrier per K-step; __syncthreads' implicit vmcnt(0)+lgkmcnt(0) drain orders it).
// blockIdx.y = split-K chunk: offsets A,B by y*K and C (EPI=0) by y*M*N.
// EPI 0: bf16 C (partial slab or direct).  EPI 1: fp32 C = resid + acc.
template <int EPI, bool DBUF>
__global__ __launch_bounds__(256) void gemm_bt(const u16* __restrict__ A, int lda,
                                               const u16* __restrict__ B, int ldb,
                                               void* __restrict__ C,
                                               const float* __restrict__ resid,
                                               int M, int N, int K) {
  __shared__ __align__(16) u16 As[(DBUF ? 2 : 1) * 128 * 64];
  __shared__ __align__(16) u16 Bs[(DBUF ? 2 : 1) * 128 * 64];
  const int tid = threadIdx.x;
  const int lane = tid & 63;
  const int w = tid >> 6;
  const int wr = (w >> 1) << 6;
  const int wc = (w & 1) << 6;
  const int nbn = N >> 7;
  const int m0 = (blockIdx.x / nbn) << 7;
  const int n0 = (blockIdx.x % nbn) << 7;
  const int l15 = lane & 15;
  const int lhi = lane >> 4;
  A += (size_t)blockIdx.y * K;               // split-K chunk offset (elements)
  B += (size_t)blockIdx.y * K;

  f32x4 acc[4][4] = {};

  auto stage = [&](int buf, int k0) {
#pragma unroll
    for (int p = 0; p < 4; ++p) {
      const int c = p * 256 + tid;           // 16B chunk id, 1024 chunks = 16KB tile
      const int row = c >> 3;
      const int cb = (c & 7) << 4;
      const int src = cb ^ ((row & 7) << 4); // pre-swizzle source column
      async16((char*)As + buf * 16384 + c * 16,
              (const char*)A + ((size_t)(m0 + row) * lda + k0) * 2 + src);
      async16((char*)Bs + buf * 16384 + c * 16,
              (const char*)B + ((size_t)(n0 + row) * ldb + k0) * 2 + src);
    }
  };
  auto compute = [&](int buf) {
#pragma unroll
    for (int kk = 0; kk < 2; ++kk) {
      bf16x8 af[4], bfr[4];
#pragma unroll
      for (int m = 0; m < 4; ++m) {
        const int row = wr + (m << 4) + l15;
        const int off = row * 128 + (((kk << 6) + (lhi << 4)) ^ ((row & 7) << 4));
        af[m] = *(const bf16x8*)((const char*)As + buf * 16384 + off);
      }
#pragma unroll
      for (int n = 0; n < 4; ++n) {
        const int row = wc + (n << 4) + l15;
        const int off = row * 128 + (((kk << 6) + (lhi << 4)) ^ ((row & 7) << 4));
        bfr[n] = *(const bf16x8*)((const char*)Bs + buf * 16384 + off);
      }
#pragma unroll
      for (int m = 0; m < 4; ++m)
#pragma unroll
        for (int n = 0; n < 4; ++n)
          acc[m][n] = MFMA(af[m], bfr[n], acc[m][n]);
    }
  };

  if (DBUF) {
    stage(0, 0);
    __syncthreads();                         // buf0 staged (vmcnt drained)
    int cur = 0;
    for (int k0 = 0; k0 < K; k0 += 64) {
      if (k0 + 64 < K) stage(cur ^ 1, k0 + 64);  // issue next-tile loads first
      compute(cur);                          // ds_read + MFMA on current
      __syncthreads();                       // drains vmcnt (next staged) + lgkm
      cur ^= 1;
    }
  } else {
    for (int k0 = 0; k0 < K; k0 += 64) {
      stage(0, k0);
      __syncthreads();
      compute(0);
      __syncthreads();
    }
  }

  u16* Cp = (u16*)C + (size_t)blockIdx.y * M * N;  // split-K partial slab (EPI=0)
#pragma unroll
  for (int m = 0; m < 4; ++m) {
#pragma unroll
    for (int n = 0; n < 4; ++n) {
      const int col = n0 + wc + (n << 4) + l15;
#pragma unroll
      for (int r = 0; r < 4; ++r) {
        const int row = m0 + wr + (m << 4) + (lhi << 2) + r;  // C/D: col=lane&15, row=(lane>>4)*4+r
        const float v = acc[m][n][r];
        if (EPI == 0) {
          Cp[(size_t)row * N + col] = f2bf(v);
        } else {
          const size_t idx = (size_t)row * N + col;
          ((float*)C)[idx] = resid[idx] + v;
        }
      }
    }
  }
}

// ---------------- QKV GEMM: 64x128 tile for full chip fill ------------------------
// C[2048][3072] = H[2048][1024] @ WQKV[3072][1024]^T. The 128² tile gives only 384
// blocks = 1.5/CU (75% fill: 256 run, then a half-idle wave of 128). 64x128 tile ->
// 32x24 = 768 blocks = 3/CU EXACT fill. Same staging idiom/swizzle/dbuf sync as
// proven gemm_bt (geometry reshape only, like ffn1-v2): 4 waves side-by-side, each
// 64 rows x 32 cols; acc[4][2]; A 8KB + B 16KB per buffer -> 48KB LDS.
__global__ __launch_bounds__(256) void gemm_qkv(const u16* __restrict__ A,
                                                const u16* __restrict__ B,
                                                u16* __restrict__ C) {
  __shared__ __align__(16) u16 As[2][64 * 64];
  __shared__ __align__(16) u16 Bs[2][128 * 64];
  const int tid = threadIdx.x;
  const int lane = tid & 63;
  const int w = tid >> 6;
  const int m0 = (blockIdx.x / 24) << 6;     // 32 M-tiles x 24 N-tiles = 768 blocks
  const int n0 = (blockIdx.x % 24) << 7;
  const int l15 = lane & 15;
  const int lhi = lane >> 4;

  f32x4 acc[4][2] = {};

  auto stage = [&](int buf, int k0) {
#pragma unroll
    for (int p = 0; p < 2; ++p) {            // A: 512 chunks (64 rows)
      const int c = p * 256 + tid;
      const int row = c >> 3;
      const int cb = (c & 7) << 4;
      const int src = cb ^ ((row & 7) << 4);
      async16((char*)As[buf] + c * 16,
              (const char*)A + ((size_t)(m0 + row) * 1024 + k0) * 2 + src);
    }
#pragma unroll
    for (int p = 0; p < 4; ++p) {            // B: 1024 chunks (128 rows)
      const int c = p * 256 + tid;
      const int row = c >> 3;
      const int cb = (c & 7) << 4;
      const int src = cb ^ ((row & 7) << 4);
      async16((char*)Bs[buf] + c * 16,
              (const char*)B + ((size_t)(n0 + row) * 1024 + k0) * 2 + src);
    }
  };
  auto compute = [&](int buf) {
#pragma unroll
    for (int kk = 0; kk < 2; ++kk) {
      bf16x8 af[4], bfr[2];
#pragma unroll
      for (int m = 0; m < 4; ++m) {
        const int row = (m << 4) + l15;
        const int off = row * 128 + (((kk << 6) + (lhi << 4)) ^ ((row & 7) << 4));
        af[m] = *(const bf16x8*)((const char*)As[buf] + off);
      }
#pragma unroll
      for (int n = 0; n < 2; ++n) {
        const int row = (w << 5) + (n << 4) + l15;
        const int off = row * 128 + (((kk << 6) + (lhi << 4)) ^ ((row & 7) << 4));
        bfr[n] = *(const bf16x8*)((const char*)Bs[buf] + off);
      }
#pragma unroll
      for (int m = 0; m < 4; ++m)
#pragma unroll
        for (int n = 0; n < 2; ++n)
          acc[m][n] = MFMA(af[m], bfr[n], acc[m][n]);
    }
  };

  stage(0, 0);
  __syncthreads();
  int cur = 0;
  for (int k0 = 0; k0 < 1024; k0 += 64) {
    if (k0 + 64 < 1024) stage(cur ^ 1, k0 + 64);
    compute(cur);
    __syncthreads();
    cur ^= 1;
  }

#pragma unroll
  for (int m = 0; m < 4; ++m)
#pragma unroll
    for (int n = 0; n < 2; ++n) {
      const int col = n0 + (w << 5) + (n << 4) + l15;
#pragma unroll
      for (int r = 0; r < 4; ++r) {
        const int row = m0 + (m << 4) + (lhi << 2) + r;
        C[(size_t)row * 3072 + col] = f2bf(acc[m][n][r]);
      }
    }
}

// ---------------- fused FFN1 (v2): hid = gate*rsig(gate)*val ----------------------
// Each block: 128x64 gate tile + 128x64 val tile (same output cols), proven dbuf
// structure (32KB/buffer, 64KB LDS, 2 blocks/CU). Wave computes 64x32 of both ->
// swiglu pairing in-register; 8 ds_read_b128 : 16 MFMA per kk as proven gemm_bt.
__global__ __launch_bounds__(256) void gemm_ffn1(const u16* __restrict__ A,
                                                 const u16* __restrict__ B,
                                                 u16* __restrict__ hid) {
  __shared__ __align__(16) u16 As[2][128 * 64];
  __shared__ __align__(16) u16 Bg[2][64 * 64];
  __shared__ __align__(16) u16 Bv[2][64 * 64];
  const int tid = threadIdx.x;
  const int lane = tid & 63;
  const int w = tid >> 6;
  const int wr = (w >> 1) << 6;              // row offset (0/64)
  const int wc = (w & 1) << 5;               // col offset within 64-col tile (0/32)
  const int m0 = (blockIdx.x >> 6) << 7;     // 16 M-tiles x 64 N-tiles = 1024 blocks
  const int n0 = (blockIdx.x & 63) << 6;
  const int l15 = lane & 15;
  const int lhi = lane >> 4;

  f32x4 ag[4][2] = {};                       // gate acc (32 AGPR)
  f32x4 av[4][2] = {};                       // val acc (32 AGPR)

  auto stage = [&](int buf, int k0) {
#pragma unroll
    for (int p = 0; p < 4; ++p) {            // A: 1024 chunks
      const int c = p * 256 + tid;
      const int row = c >> 3;
      const int cb = (c & 7) << 4;
      const int src = cb ^ ((row & 7) << 4);
      async16((char*)As[buf] + c * 16,
              (const char*)A + ((size_t)(m0 + row) * 1024 + k0) * 2 + src);
    }
#pragma unroll
    for (int p = 0; p < 2; ++p) {            // Bg/Bv: 512 chunks each
      const int c = p * 256 + tid;
      const int row = c >> 3;                // 0..63
      const int cb = (c & 7) << 4;
      const int src = cb ^ ((row & 7) << 4);
      async16((char*)Bg[buf] + c * 16,
              (const char*)B + ((size_t)(n0 + row) * 1024 + k0) * 2 + src);
      async16((char*)Bv[buf] + c * 16,
              (const char*)B + ((size_t)(4096 + n0 + row) * 1024 + k0) * 2 + src);
    }
  };
  auto compute = [&](int buf) {
#pragma unroll
    for (int kk = 0; kk < 2; ++kk) {
      bf16x8 af[4], bgf[2], bvf[2];
#pragma unroll
      for (int m = 0; m < 4; ++m) {
        const int row = wr + (m << 4) + l15;
        const int off = row * 128 + (((kk << 6) + (lhi << 4)) ^ ((row & 7) << 4));
        af[m] = *(const bf16x8*)((const char*)As[buf] + off);
      }
#pragma unroll
      for (int n = 0; n < 2; ++n) {
        const int row = wc + (n << 4) + l15;
        const int off = row * 128 + (((kk << 6) + (lhi << 4)) ^ ((row & 7) << 4));
        bgf[n] = *(const bf16x8*)((const char*)Bg[buf] + off);
        bvf[n] = *(const bf16x8*)((const char*)Bv[buf] + off);
      }
#pragma unroll
      for (int m = 0; m < 4; ++m)
#pragma unroll
        for (int n = 0; n < 2; ++n) {
          ag[m][n] = MFMA(af[m], bgf[n], ag[m][n]);
          av[m][n] = MFMA(af[m], bvf[n], av[m][n]);
        }
    }
  };

  stage(0, 0);
  __syncthreads();
  int cur = 0;
  for (int k0 = 0; k0 < 1024; k0 += 64) {
    if (k0 + 64 < 1024) stage(cur ^ 1, k0 + 64);
    compute(cur);
    __syncthreads();
    cur ^= 1;
  }

#pragma unroll
  for (int m = 0; m < 4; ++m) {
#pragma unroll
    for (int n = 0; n < 2; ++n) {
      const int col = n0 + wc + (n << 4) + l15;
#pragma unroll
      for (int r = 0; r < 4; ++r) {
        const int row = m0 + wr + (m << 4) + (lhi << 2) + r;
        const float g = ag[m][n][r];
        const float v = av[m][n][r];
        hid[(size_t)row * 4096 + col] = f2bf(g * rsig_fast(g) * v);
      }
    }
  }
}

// ---------------- split-K reduce: out = [resid +] sum_c part[c] -------------------
// NC chunks, cstride = elems per chunk slab. BF16OUT: bf16 out, no resid.
template <int NC, bool BF16OUT>
__global__ __launch_bounds__(256) void splitk_reduce(const u16* __restrict__ part,
                                                     size_t cstride,
                                                     const float* __restrict__ resid,
                                                     void* __restrict__ out) {
  const size_t i = ((size_t)blockIdx.x * 256 + threadIdx.x) * 8;
  float acc[8];
  if constexpr (BF16OUT) {
#pragma unroll
    for (int j = 0; j < 8; ++j) acc[j] = 0.f;
  } else {
    const float4 r0 = *(const float4*)(resid + i);
    const float4 r1 = *(const float4*)(resid + i + 4);
    acc[0] = r0.x; acc[1] = r0.y; acc[2] = r0.z; acc[3] = r0.w;
    acc[4] = r1.x; acc[5] = r1.y; acc[6] = r1.z; acc[7] = r1.w;
  }
#pragma unroll
  for (int c = 0; c < NC; ++c) {
    const uint4 p = *(const uint4*)(part + (size_t)c * cstride + i);
    const u16* ps = (const u16*)&p;
#pragma unroll
    for (int j = 0; j < 8; ++j) acc[j] += bf2f(ps[j]);
  }
  if constexpr (BF16OUT) {
    u16 ob[8];
#pragma unroll
    for (int j = 0; j < 8; ++j) ob[j] = f2bf(acc[j]);
    *(uint4*)((u16*)out + i) = *(const uint4*)ob;
  } else {
    float4 o0 = {acc[0], acc[1], acc[2], acc[3]};
    float4 o1 = {acc[4], acc[5], acc[6], acc[7]};
    *(float4*)((float*)out + i) = o0;
    *(float4*)((float*)out + i + 4) = o1;
  }
}

// ---------------- V transpose: qkv[:,2048+h*64+d] -> vt[(h*64+d)][t] --------------
__global__ __launch_bounds__(256) void transpose_v(const u16* __restrict__ qkv,
                                                   u16* __restrict__ vt) {
  __shared__ __align__(16) u16 tile[64][72];   // 144B row stride = 9*16B, aligned
  const int head = blockIdx.x >> 5;
  const int t0 = (blockIdx.x & 31) << 6;
  const int tid = threadIdx.x;
  const int row = tid >> 2;            // t within tile (load) / d (store)
  const int cb = (tid & 3) << 4;       // 16-elem chunk
  const u16* src = qkv + (size_t)(t0 + row) * 3072 + 2048 + head * 64 + cb;
  *(uint4*)&tile[row][cb] = *(const uint4*)src;
  *(uint4*)&tile[row][cb + 8] = *(const uint4*)(src + 8);
  __syncthreads();
  u16 buf[16];
#pragma unroll
  for (int j = 0; j < 16; ++j) buf[j] = tile[cb + j][row];
  u16* dst = vt + (size_t)(head * 64 + row) * 2048 + t0 + cb;
  *(uint4*)dst = *(const uint4*)&buf[0];
  *(uint4*)(dst + 8) = *(const uint4*)&buf[8];
}

// ---------------- attention phase A (v4, R13-measured): QBLK=128, KVBLK=64 --------
// R16 post-mortem: v5 (KVBLK=128, 80KB LDS) was +0.6us vs v4 — occupancy drop
// (3->2 blocks/CU) canceled the drain halving. REVERTED to the R13-measured v4:
// 8 waves x 16 q-rows, K/V dbuf 64-wide, 48KB LDS (3 blocks/CU), compact LPT grid.
__global__ __launch_bounds__(512) void attn_part(const u16* __restrict__ qkv,
                                                 const u16* __restrict__ vt,
                                                 u16* __restrict__ pnum,
                                                 float* __restrict__ pden) {
  const int id = blockIdx.x;
  const int head = id & 15;
  const int rem = id >> 4;                       // [0,40)
  int qb2, c;
  if (rem < 4)       { qb2 = 4 + rem;                          c = 0; }
  else if (rem < 12) { const int t = rem - 4;  qb2 = 8 + (t >> 1);  c = t & 1; }
  else if (rem < 24) { const int t = rem - 12; qb2 = 12 + t / 3;    c = t % 3; }
  else               { const int t = rem - 24; qb2 = ((t & 3) << 2) + 3 - (t >> 2); c = qb2 >> 2; }
  const int a2 = qb2 >> 2, b2 = qb2 & 3;
  const int slot = head * 40 + ((a2 * (a2 + 1)) << 1) + b2 * (a2 + 1) + c;

  __shared__ __align__(16) u16 Ks[2][64 * 64];
  __shared__ __align__(16) u16 Vs[2][64 * 64];  // V^T tiles: [d][s]
  __shared__ __align__(16) u16 QP[8][16 * 64];  // Q staging ALIASED w/ per-wave P scratch
  const int tid = threadIdx.x;
  const int lane = tid & 63;
  const int w = tid >> 6;                        // [0,8)
  const int l15 = lane & 15;
  const int lhi = lane >> 4;
  const int qbase = qb2 << 7;                    // 128 q-rows per block
  const float slope = exp2f(-0.5f * (float)(head + 1));

  auto stageKV = [&](int buf, int s0) {          // 512 chunks each, 1 per thread
    const int row = tid >> 3;
    const int cb = (tid & 7) << 4;
    const int src = cb ^ ((row & 7) << 4);
    async16((char*)Ks[buf] + tid * 16,
            (const char*)qkv + ((size_t)(s0 + row) * 3072 + 1024 + head * 64) * 2 + src);
    async16((char*)Vs[buf] + tid * 16,
            (const char*)vt + ((size_t)(head * 64 + row) * 2048 + s0) * 2 + src);
  };

  const int sfirst = c << 9;
  const int smax = min(qbase + 64, sfirst + 448);  // last KV tile (s0 <= max q row)
#pragma unroll
  for (int p = 0; p < 2; ++p) {                  // stage Q (128 rows, 1024 chunks)
    const int cc = p * 512 + tid;
    const int row = cc >> 3;
    const int cb = (cc & 7) << 4;
    const int src = cb ^ ((row & 7) << 4);
    async16((char*)QP + cc * 16,
            (const char*)qkv + ((size_t)(qbase + row) * 3072 + head * 64) * 2 + src);
  }
  stageKV(0, sfirst);
  __syncthreads();                               // Q + buf0 staged (vmcnt drained)

  bf16x8 qf[2];                                  // wave w reads only its own stripe QP[w]
#pragma unroll
  for (int kk = 0; kk < 2; ++kk) {
    const int row = (w << 4) + l15;
    const int off = row * 128 + (((kk << 6) + (lhi << 4)) ^ ((row & 7) << 4));
    qf[kk] = *(const bf16x8*)((const char*)QP + off);
  }

  f32x4 oacc[4] = {};
  float rs[4] = {0.f, 0.f, 0.f, 0.f};
  u16* pw = (u16*)QP[w];
  int cur = 0;

  for (int s0 = sfirst; s0 <= smax; s0 += 64) {
    if (s0 + 64 <= smax) stageKV(cur ^ 1, s0 + 64);  // issue next-tile loads first
    const char* Kc = (const char*)Ks[cur];
    const char* Vc = (const char*)Vs[cur];

    bf16x8 kf[4][2];                             // phase 1: all K-frag reads
#pragma unroll
    for (int bb = 0; bb < 4; ++bb)
#pragma unroll
      for (int kk = 0; kk < 2; ++kk) {
        const int row = (bb << 4) + l15;
        const int off = row * 128 + (((kk << 6) + (lhi << 4)) ^ ((row & 7) << 4));
        kf[bb][kk] = *(const bf16x8*)(Kc + off);
      }
    f32x4 sa[4];                                 // phase 2: all QK MFMAs
#pragma unroll
    for (int bb = 0; bb < 4; ++bb) {
      f32x4 z = {0.f, 0.f, 0.f, 0.f};
      z = MFMA(qf[0], kf[bb][0], z);
      sa[bb] = MFMA(qf[1], kf[bb][1], z);
    }
#pragma unroll
    for (int bb = 0; bb < 4; ++bb) {             // phase 3: p4 + P-writes (16 elems)
      const int s_abs = s0 + (bb << 4) + l15;
#pragma unroll
      for (int r = 0; r < 4; ++r) {
        const int prow = (lhi << 2) + r;
        const int q_abs = qbase + (w << 4) + prow;
        float p4 = 0.f;
        if (s_abs <= q_abs) {                    // masked: ref value ~6e-19, skip
          const float sc = sa[bb][r] * 0.125f - slope * (float)(q_abs - s_abs);
          const float t = rsig_fast(sc);
          const float t2 = t * t;
          p4 = t2 * t2;
        }
        rs[r] += p4;
        const int pcol2 = ((bb << 4) + l15) << 1;
        const int poff = prow * 128 + (pcol2 ^ ((prow & 7) << 4));
        *(u16*)((char*)pw + poff) = f2bf(p4);    // D-layout -> swizzled LDS
      }
    }
    bf16x8 pf[2];                                // phase 4: reload P in A-layout
#pragma unroll
    for (int kk = 0; kk < 2; ++kk) {
      const int row = l15;
      const int off = row * 128 + (((kk << 6) + (lhi << 4)) ^ ((row & 7) << 4));
      pf[kk] = *(const bf16x8*)((const char*)pw + off);
    }
#pragma unroll
    for (int db = 0; db < 4; ++db) {             // phase 5: PV
#pragma unroll
      for (int kk = 0; kk < 2; ++kk) {
        const int row = (db << 4) + l15;         // row of V^T = d
        const int off = row * 128 + (((kk << 6) + (lhi << 4)) ^ ((row & 7) << 4));
        const bf16x8 vf = *(const bf16x8*)(Vc + off);
        oacc[db] = MFMA(pf[kk], vf, oacc[db]);
      }
    }
    __syncthreads();                             // next buf staged + all reads done
    cur ^= 1;
  }

#pragma unroll
  for (int r = 0; r < 4; ++r) {                  // row-sum of p4 over the 16-lane group
    float v = rs[r];
    v += __shfl_xor(v, 1);
    v += __shfl_xor(v, 2);
    v += __shfl_xor(v, 4);
    v += __shfl_xor(v, 8);
    rs[r] = v;
  }
  if (l15 == 0) {                                // one writer per q-row (128 rows)
#pragma unroll
    for (int r = 0; r < 4; ++r)
      pden[(size_t)slot * 128 + (w << 4) + (lhi << 2) + r] = rs[r];
  }
  __syncthreads();
#pragma unroll
  for (int db = 0; db < 4; ++db)                 // pack partial num into LDS (linear)
#pragma unroll
    for (int r = 0; r < 4; ++r)
      pw[((lhi << 2) + r) * 64 + (db << 4) + l15] = f2bf(oacc[db][r]);
  __syncthreads();
  {                                              // coalesced 16B stores of num
    const int row = lane >> 2;
    const int cb = (lane & 3) << 4;
    const u16* s = pw + row * 64 + cb;
    const uint4 d0 = *(const uint4*)s;
    const uint4 d1 = *(const uint4*)(s + 8);
    u16* dst = pnum + (size_t)slot * 8192 + ((w << 4) + row) * 64 + cb;
    *(uint4*)dst = d0;
    *(uint4*)(dst + 8) = d1;
  }
}

// ---------------- attention phase B: merge partials, divide, write ATTN -----------
// Block = one (head, 64-row q-tile); maps into its 128-row slot group (qb2 = qb>>1).
__global__ __launch_bounds__(256) void attn_merge(const u16* __restrict__ pnum,
                                                  const float* __restrict__ pden,
                                                  u16* __restrict__ out) {
  const int head = blockIdx.x >> 5;
  const int qb = blockIdx.x & 31;
  const int qb2 = qb >> 1;
  const int a2 = qb >> 3;                        // == qb2>>2
  const int nc = a2 + 1;
  const int slot0 = head * 40 + ((a2 * (a2 + 1)) << 1) + (qb2 & 3) * (a2 + 1);
  const int tid = threadIdx.x;
  const int row = tid >> 2;
  const int c0 = (tid & 3) << 4;
  const int rr = ((qb & 1) << 6) + row;          // row within 128-row slot

  float acc[16] = {};
  float den = 0.f;
  for (int ci = 0; ci < nc; ++ci) {
    const int slot = slot0 + ci;
    den += pden[(size_t)slot * 128 + rr];
    const u16* np = pnum + (size_t)slot * 8192 + rr * 64 + c0;
    const uint4 n0 = *(const uint4*)np;
    const uint4 n1 = *(const uint4*)(np + 8);
    const u16* ns0 = (const u16*)&n0;
    const u16* ns1 = (const u16*)&n1;
#pragma unroll
    for (int j = 0; j < 8; ++j) {
      acc[j] += bf2f(ns0[j]);
      acc[8 + j] += bf2f(ns1[j]);
    }
  }
  const float inv = 1.f / (den + 1e-6f);
  u16 ob[16];
#pragma unroll
  for (int j = 0; j < 16; ++j) ob[j] = f2bf(acc[j] * inv);
  u16* dst = out + (size_t)((qb << 6) + row) * 1024 + head * 64 + c0;
  *(uint4*)dst = *(const uint4*)&ob[0];
  *(uint4*)(dst + 8) = *(const uint4*)&ob[8];
}

// ------------------------------- launcher ----------------------------------------
extern "C" void kernel_launch(void* const* d_in, const int* in_sizes, int n_in,
                              void* d_out, int out_size, void* d_ws, size_t ws_size,
                              hipStream_t stream) {
  const float* x     = (const float*)d_in[0];
  const float* wqkv  = (const float*)d_in[1];
  const float* wout  = (const float*)d_in[2];
  const float* wmer  = (const float*)d_in[3];
  const float* w3    = (const float*)d_in[4];
  const float* n1w   = (const float*)d_in[5];
  const float* n2w   = (const float*)d_in[6];
  char* ws = (char*)d_ws;

  // workspace layout (bytes), total 79,691,776 — byte-identical to R13.
  u16*   WQKV = (u16*)(ws + 0);            // [3072][1024] bf16, 6MB   conv->qkvgemm
  u16*   WOUT = (u16*)(ws + 6291456);      // [1024][1024], 2MB        conv->woutgemm
  u16*   WMER = (u16*)(ws + 8388608);      // [8192][1024], 16MB       conv->ffn1
  u16*   W3B  = (u16*)(ws + 25165824);     // [1024][4096], 8MB        conv->w3gemm
  u16*   H    = (u16*)(ws + 33554432);     // [2048][1024], 4MB        mrnorm1->qkvgemm
  u16*   QKV  = (u16*)(ws + 37748736);     // [2048][3072], 12MB       qkvgemm->attn (direct)
  u16*   VT   = (u16*)(ws + 50331648);     // [1024][2048], 4MB        transpose->attn
  u16*   PNUM = (u16*)(ws + 54525952);     // [640][128][64] bf16, 10MB attn_part->merge
  float* PDEN = (float*)(ws + 65011712);   // [640][128] fp32, 0.33MB
  u16*   ATTN = (u16*)(ws + 65536000);     // [2048][1024], 4MB        merge->woutgemm
  u16*   WOP  = (u16*)(ws + 37748736);     // [4][2048][1024], 16MB    (aliases dead QKV+VT)
  float* X1   = (float*)(ws + 54525952);   // [2048][1024] fp32, 8MB   (aliases dead PNUM)
  u16*   H2   = (u16*)(ws + 33554432);     // 4MB (aliases dead H)     mrnorm2->ffn1
  u16*   HID  = (u16*)(ws + 37748736);     // [2048][4096], 16MB (aliases dead WOP)
  u16*   W3P  = (u16*)(ws + 62914560);     // [4][2048][1024], 16MB (aliases dead ATTN) ->79691776

  to_bf16_all<<<8192, 256, 0, stream>>>(wqkv, WQKV, wout, WOUT, wmer, WMER, w3, W3B);

  mrnorm<<<2048, 256, 0, stream>>>(x, n1w, H);
  // QKV GEMM: 64x128 tile, 768 blocks = 3/CU exact fill (vs 384 = 75% fill)
  gemm_qkv<<<768, 256, 0, stream>>>(H, WQKV, QKV);
  transpose_v<<<512, 256, 0, stream>>>(QKV, VT);
  // attn v4 (R13-measured): QBLK=128, KVBLK=64; 640 blocks, LPT-ordered
  attn_part<<<640, 512, 0, stream>>>(QKV, VT, PNUM, PDEN);
  attn_merge<<<512, 256, 0, stream>>>(PNUM, PDEN, ATTN);
  // wout split-K=4 (R12-verified): reduce adds resid x -> X1.
  gemm_bt<0, true><<<dim3(16 * 8, 4), 256, 0, stream>>>(ATTN, 1024, WOUT, 1024, WOP,
                                                        nullptr, 2048, 1024, 256);
  splitk_reduce<4, false><<<1024, 256, 0, stream>>>(WOP, 2097152, x, X1);

  mrnorm<<<2048, 256, 0, stream>>>(X1, n2w, H2);
  // fused FFN1 v2: 1024 blocks, dbuf, 128x64 gate + 128x64 val per block
  gemm_ffn1<<<1024, 256, 0, stream>>>(H2, WMER, HID);
  // w3 split-K=4: 512 blocks, 16 K-steps/chunk; reduce adds resid X1 -> out.
  gemm_bt<0, true><<<dim3(16 * 8, 4), 256, 0, stream>>>(HID, 4096, W3B, 4096, W3P,
                                                        nullptr, 2048, 1024, 1024);
  splitk_reduce<4, false><<<1024, 256, 0, stream>>>(W3P, 2097152, X1, (float*)d_out);
}

// Round 18
// 165.129 us; speedup vs baseline: 1.0083x; 1.0083x over previous
//
#include <hip/hip_runtime.h>
#include <hip/hip_bf16.h>
#include <stdint.h>

typedef unsigned int u32;
typedef unsigned short u16;
typedef __attribute__((ext_vector_type(8))) short bf16x8;   // 8 bf16 = 4 VGPRs
typedef __attribute__((ext_vector_type(4))) float f32x4;

#define MFMA(a, b, c) __builtin_amdgcn_mfma_f32_16x16x32_bf16(a, b, c, 0, 0, 0)

__device__ __forceinline__ u16 f2bf(float f) {            // RNE float->bf16
  u32 u = __float_as_uint(f);
  return (u16)((u + 0x7FFFu + ((u >> 16) & 1u)) >> 16);
}
__device__ __forceinline__ float bf2f(u16 h) {
  return __uint_as_float(((u32)h) << 16);
}
// rational sigmoid via v_rcp (1 trans op instead of ~10-op exact-div sequence)
__device__ __forceinline__ float rsig_fast(float sc) {
  return 0.5f + 0.5f * sc * __builtin_amdgcn_rcpf(fabsf(sc) + 1.f);
}
// async global->LDS, 16B per lane. LDS dest is wave-uniform base + lane*16 (linear).
__device__ __forceinline__ void async16(void* lds, const void* g) {
  __builtin_amdgcn_global_load_lds((const __attribute__((address_space(1))) u32*)g,
                                   (__attribute__((address_space(3))) u32*)lds, 16, 0, 0);
}

// ---------------- fp32 -> bf16 weight conversion, all 4 weights in one launch -----
__global__ __launch_bounds__(256) void to_bf16_all(const float* __restrict__ s0, u16* __restrict__ d0,
                                                   const float* __restrict__ s1, u16* __restrict__ d1,
                                                   const float* __restrict__ s2, u16* __restrict__ d2,
                                                   const float* __restrict__ s3, u16* __restrict__ d3) {
  int b = blockIdx.x;                        // segs: 1536 | 512 | 4096 | 2048 blocks
  const float* src; u16* dst;
  if (b < 1536)      { src = s0; dst = d0; }
  else if (b < 2048) { src = s1; dst = d1; b -= 1536; }
  else if (b < 6144) { src = s2; dst = d2; b -= 2048; }
  else               { src = s3; dst = d3; b -= 6144; }
  const size_t i = (size_t)b * 256 + threadIdx.x;
  const float4 a = ((const float4*)src)[2 * i];
  const float4 c = ((const float4*)src)[2 * i + 1];
  ushort4 o0, o1;
  o0.x = f2bf(a.x); o0.y = f2bf(a.y); o0.z = f2bf(a.z); o0.w = f2bf(a.w);
  o1.x = f2bf(c.x); o1.y = f2bf(c.y); o1.z = f2bf(c.z); o1.w = f2bf(c.w);
  ((ushort4*)dst)[2 * i] = o0;
  ((ushort4*)dst)[2 * i + 1] = o1;
}

// ---------------- mr_norm: x / (mean|x| + eps) * w  -> bf16, one block per row ----
__global__ __launch_bounds__(256) void mrnorm(const float* __restrict__ x,
                                              const float* __restrict__ wg,
                                              u16* __restrict__ out) {
  const int row = blockIdx.x;
  const int tid = threadIdx.x;
  const float4 v = ((const float4*)(x + (size_t)row * 1024))[tid];
  float s = fabsf(v.x) + fabsf(v.y) + fabsf(v.z) + fabsf(v.w);
#pragma unroll
  for (int off = 1; off < 64; off <<= 1) s += __shfl_xor(s, off);
  __shared__ float red[4];
  if ((tid & 63) == 0) red[tid >> 6] = s;
  __syncthreads();
  const float inv = 1.f / ((red[0] + red[1] + red[2] + red[3]) * (1.f / 1024.f) + 1e-6f);
  const float4 g = ((const float4*)wg)[tid];
  ushort4 o;
  o.x = f2bf(v.x * inv * g.x);
  o.y = f2bf(v.y * inv * g.y);
  o.z = f2bf(v.z * inv * g.z);
  o.w = f2bf(v.w * inv * g.w);
  ((ushort4*)out)[(size_t)row * 256 + tid] = o;
}

// ---------------- fused wout-reduce + mr_norm (one block per row) -----------------
// X1 = x + sum_c part[c]  (fp32, kept as resid for w3);  H2 = mrnorm(X1)*w (bf16).
// Replaces splitk_reduce<4,false> + mrnorm: saves an 8MB X1 re-read + a launch.
__global__ __launch_bounds__(256) void wout_reduce_norm(const u16* __restrict__ part,
                                                        const float* __restrict__ x,
                                                        const float* __restrict__ wg,
                                                        float* __restrict__ x1,
                                                        u16* __restrict__ h2) {
  const int row = blockIdx.x;
  const int tid = threadIdx.x;
  const size_t base = (size_t)row * 1024 + tid * 4;
  float4 a = *(const float4*)(x + base);
#pragma unroll
  for (int c = 0; c < 4; ++c) {              // partial slabs: [4][2048][1024] bf16
    const ushort4 p = *(const ushort4*)(part + (size_t)c * 2097152 + base);
    a.x += bf2f(p.x); a.y += bf2f(p.y); a.z += bf2f(p.z); a.w += bf2f(p.w);
  }
  *(float4*)(x1 + base) = a;
  float s = fabsf(a.x) + fabsf(a.y) + fabsf(a.z) + fabsf(a.w);
#pragma unroll
  for (int off = 1; off < 64; off <<= 1) s += __shfl_xor(s, off);
  __shared__ float red[4];
  if ((tid & 63) == 0) red[tid >> 6] = s;
  __syncthreads();
  const float inv = 1.f / ((red[0] + red[1] + red[2] + red[3]) * (1.f / 1024.f) + 1e-6f);
  const float4 g = ((const float4*)wg)[tid];
  ushort4 o;
  o.x = f2bf(a.x * inv * g.x);
  o.y = f2bf(a.y * inv * g.y);
  o.z = f2bf(a.z * inv * g.z);
  o.w = f2bf(a.w * inv * g.w);
  ((ushort4*)h2)[(size_t)row * 256 + tid] = o;
}

// ---------------- GEMM: C[M][N] = A[M][K] @ B[N][K]^T  (bf16 in, fp32 acc) --------
// 128x128 tile, BK=64, 256 thr = 4 waves (2x2), each wave 64x64 via 4x4 16x16x32 MFMA.
// LDS staged by global_load_lds (linear dest) with XOR-swizzled SOURCE column;
// ds_read_b128 applies the same XOR -> bank-conflict-free (T2 / G21).
// DBUF=true: 2-phase double-buffer. blockIdx.y = split-K chunk.
// EPI 0: bf16 C (partial slab or direct).  EPI 1: fp32 C = resid + acc.
template <int EPI, bool DBUF>
__global__ __launch_bounds__(256) void gemm_bt(const u16* __restrict__ A, int lda,
                                               const u16* __restrict__ B, int ldb,
                                               void* __restrict__ C,
                                               const float* __restrict__ resid,
                                               int M, int N, int K) {
  __shared__ __align__(16) u16 As[(DBUF ? 2 : 1) * 128 * 64];
  __shared__ __align__(16) u16 Bs[(DBUF ? 2 : 1) * 128 * 64];
  const int tid = threadIdx.x;
  const int lane = tid & 63;
  const int w = tid >> 6;
  const int wr = (w >> 1) << 6;
  const int wc = (w & 1) << 6;
  const int nbn = N >> 7;
  const int m0 = (blockIdx.x / nbn) << 7;
  const int n0 = (blockIdx.x % nbn) << 7;
  const int l15 = lane & 15;
  const int lhi = lane >> 4;
  A += (size_t)blockIdx.y * K;               // split-K chunk offset (elements)
  B += (size_t)blockIdx.y * K;

  f32x4 acc[4][4] = {};

  auto stage = [&](int buf, int k0) {
#pragma unroll
    for (int p = 0; p < 4; ++p) {
      const int c = p * 256 + tid;           // 16B chunk id, 1024 chunks = 16KB tile
      const int row = c >> 3;
      const int cb = (c & 7) << 4;
      const int src = cb ^ ((row & 7) << 4); // pre-swizzle source column
      async16((char*)As + buf * 16384 + c * 16,
              (const char*)A + ((size_t)(m0 + row) * lda + k0) * 2 + src);
      async16((char*)Bs + buf * 16384 + c * 16,
              (const char*)B + ((size_t)(n0 + row) * ldb + k0) * 2 + src);
    }
  };
  auto compute = [&](int buf) {
#pragma unroll
    for (int kk = 0; kk < 2; ++kk) {
      bf16x8 af[4], bfr[4];
#pragma unroll
      for (int m = 0; m < 4; ++m) {
        const int row = wr + (m << 4) + l15;
        const int off = row * 128 + (((kk << 6) + (lhi << 4)) ^ ((row & 7) << 4));
        af[m] = *(const bf16x8*)((const char*)As + buf * 16384 + off);
      }
#pragma unroll
      for (int n = 0; n < 4; ++n) {
        const int row = wc + (n << 4) + l15;
        const int off = row * 128 + (((kk << 6) + (lhi << 4)) ^ ((row & 7) << 4));
        bfr[n] = *(const bf16x8*)((const char*)Bs + buf * 16384 + off);
      }
#pragma unroll
      for (int m = 0; m < 4; ++m)
#pragma unroll
        for (int n = 0; n < 4; ++n)
          acc[m][n] = MFMA(af[m], bfr[n], acc[m][n]);
    }
  };

  if (DBUF) {
    stage(0, 0);
    __syncthreads();                         // buf0 staged (vmcnt drained)
    int cur = 0;
    for (int k0 = 0; k0 < K; k0 += 64) {
      if (k0 + 64 < K) stage(cur ^ 1, k0 + 64);  // issue next-tile loads first
      compute(cur);                          // ds_read + MFMA on current
      __syncthreads();                       // drains vmcnt (next staged) + lgkm
      cur ^= 1;
    }
  } else {
    for (int k0 = 0; k0 < K; k0 += 64) {
      stage(0, k0);
      __syncthreads();
      compute(0);
      __syncthreads();
    }
  }

  u16* Cp = (u16*)C + (size_t)blockIdx.y * M * N;  // split-K partial slab (EPI=0)
#pragma unroll
  for (int m = 0; m < 4; ++m) {
#pragma unroll
    for (int n = 0; n < 4; ++n) {
      const int col = n0 + wc + (n << 4) + l15;
#pragma unroll
      for (int r = 0; r < 4; ++r) {
        const int row = m0 + wr + (m << 4) + (lhi << 2) + r;  // C/D: col=lane&15, row=(lane>>4)*4+r
        const float v = acc[m][n][r];
        if (EPI == 0) {
          Cp[(size_t)row * N + col] = f2bf(v);
        } else {
          const size_t idx = (size_t)row * N + col;
          ((float*)C)[idx] = resid[idx] + v;
        }
      }
    }
  }
}

// ---------------- fused FFN1 (v2): hid = gate*rsig(gate)*val ----------------------
// Each block: 128x64 gate tile + 128x64 val tile (same output cols), proven dbuf
// structure (32KB/buffer, 64KB LDS, 2 blocks/CU). Wave computes 64x32 of both ->
// swiglu pairing in-register; 8 ds_read_b128 : 16 MFMA per kk as proven gemm_bt.
__global__ __launch_bounds__(256) void gemm_ffn1(const u16* __restrict__ A,
                                                 const u16* __restrict__ B,
                                                 u16* __restrict__ hid) {
  __shared__ __align__(16) u16 As[2][128 * 64];
  __shared__ __align__(16) u16 Bg[2][64 * 64];
  __shared__ __align__(16) u16 Bv[2][64 * 64];
  const int tid = threadIdx.x;
  const int lane = tid & 63;
  const int w = tid >> 6;
  const int wr = (w >> 1) << 6;              // row offset (0/64)
  const int wc = (w & 1) << 5;               // col offset within 64-col tile (0/32)
  const int m0 = (blockIdx.x >> 6) << 7;     // 16 M-tiles x 64 N-tiles = 1024 blocks
  const int n0 = (blockIdx.x & 63) << 6;
  const int l15 = lane & 15;
  const int lhi = lane >> 4;

  f32x4 ag[4][2] = {};                       // gate acc (32 AGPR)
  f32x4 av[4][2] = {};                       // val acc (32 AGPR)

  auto stage = [&](int buf, int k0) {
#pragma unroll
    for (int p = 0; p < 4; ++p) {            // A: 1024 chunks
      const int c = p * 256 + tid;
      const int row = c >> 3;
      const int cb = (c & 7) << 4;
      const int src = cb ^ ((row & 7) << 4);
      async16((char*)As[buf] + c * 16,
              (const char*)A + ((size_t)(m0 + row) * 1024 + k0) * 2 + src);
    }
#pragma unroll
    for (int p = 0; p < 2; ++p) {            // Bg/Bv: 512 chunks each
      const int c = p * 256 + tid;
      const int row = c >> 3;                // 0..63
      const int cb = (c & 7) << 4;
      const int src = cb ^ ((row & 7) << 4);
      async16((char*)Bg[buf] + c * 16,
              (const char*)B + ((size_t)(n0 + row) * 1024 + k0) * 2 + src);
      async16((char*)Bv[buf] + c * 16,
              (const char*)B + ((size_t)(4096 + n0 + row) * 1024 + k0) * 2 + src);
    }
  };
  auto compute = [&](int buf) {
#pragma unroll
    for (int kk = 0; kk < 2; ++kk) {
      bf16x8 af[4], bgf[2], bvf[2];
#pragma unroll
      for (int m = 0; m < 4; ++m) {
        const int row = wr + (m << 4) + l15;
        const int off = row * 128 + (((kk << 6) + (lhi << 4)) ^ ((row & 7) << 4));
        af[m] = *(const bf16x8*)((const char*)As[buf] + off);
      }
#pragma unroll
      for (int n = 0; n < 2; ++n) {
        const int row = wc + (n << 4) + l15;
        const int off = row * 128 + (((kk << 6) + (lhi << 4)) ^ ((row & 7) << 4));
        bgf[n] = *(const bf16x8*)((const char*)Bg[buf] + off);
        bvf[n] = *(const bf16x8*)((const char*)Bv[buf] + off);
      }
#pragma unroll
      for (int m = 0; m < 4; ++m)
#pragma unroll
        for (int n = 0; n < 2; ++n) {
          ag[m][n] = MFMA(af[m], bgf[n], ag[m][n]);
          av[m][n] = MFMA(af[m], bvf[n], av[m][n]);
        }
    }
  };

  stage(0, 0);
  __syncthreads();
  int cur = 0;
  for (int k0 = 0; k0 < 1024; k0 += 64) {
    if (k0 + 64 < 1024) stage(cur ^ 1, k0 + 64);
    compute(cur);
    __syncthreads();
    cur ^= 1;
  }

#pragma unroll
  for (int m = 0; m < 4; ++m) {
#pragma unroll
    for (int n = 0; n < 2; ++n) {
      const int col = n0 + wc + (n << 4) + l15;
#pragma unroll
      for (int r = 0; r < 4; ++r) {
        const int row = m0 + wr + (m << 4) + (lhi << 2) + r;
        const float g = ag[m][n][r];
        const float v = av[m][n][r];
        hid[(size_t)row * 4096 + col] = f2bf(g * rsig_fast(g) * v);
      }
    }
  }
}

// ---------------- split-K reduce: out = [resid +] sum_c part[c] -------------------
// NC chunks, cstride = elems per chunk slab. BF16OUT: bf16 out, no resid.
template <int NC, bool BF16OUT>
__global__ __launch_bounds__(256) void splitk_reduce(const u16* __restrict__ part,
                                                     size_t cstride,
                                                     const float* __restrict__ resid,
                                                     void* __restrict__ out) {
  const size_t i = ((size_t)blockIdx.x * 256 + threadIdx.x) * 8;
  float acc[8];
  if constexpr (BF16OUT) {
#pragma unroll
    for (int j = 0; j < 8; ++j) acc[j] = 0.f;
  } else {
    const float4 r0 = *(const float4*)(resid + i);
    const float4 r1 = *(const float4*)(resid + i + 4);
    acc[0] = r0.x; acc[1] = r0.y; acc[2] = r0.z; acc[3] = r0.w;
    acc[4] = r1.x; acc[5] = r1.y; acc[6] = r1.z; acc[7] = r1.w;
  }
#pragma unroll
  for (int c = 0; c < NC; ++c) {
    const uint4 p = *(const uint4*)(part + (size_t)c * cstride + i);
    const u16* ps = (const u16*)&p;
#pragma unroll
    for (int j = 0; j < 8; ++j) acc[j] += bf2f(ps[j]);
  }
  if constexpr (BF16OUT) {
    u16 ob[8];
#pragma unroll
    for (int j = 0; j < 8; ++j) ob[j] = f2bf(acc[j]);
    *(uint4*)((u16*)out + i) = *(const uint4*)ob;
  } else {
    float4 o0 = {acc[0], acc[1], acc[2], acc[3]};
    float4 o1 = {acc[4], acc[5], acc[6], acc[7]};
    *(float4*)((float*)out + i) = o0;
    *(float4*)((float*)out + i + 4) = o1;
  }
}

// ---------------- V transpose: qkv[:,2048+h*64+d] -> vt[(h*64+d)][t] --------------
__global__ __launch_bounds__(256) void transpose_v(const u16* __restrict__ qkv,
                                                   u16* __restrict__ vt) {
  __shared__ __align__(16) u16 tile[64][72];   // 144B row stride = 9*16B, aligned
  const int head = blockIdx.x >> 5;
  const int t0 = (blockIdx.x & 31) << 6;
  const int tid = threadIdx.x;
  const int row = tid >> 2;            // t within tile (load) / d (store)
  const int cb = (tid & 3) << 4;       // 16-elem chunk
  const u16* src = qkv + (size_t)(t0 + row) * 3072 + 2048 + head * 64 + cb;
  *(uint4*)&tile[row][cb] = *(const uint4*)src;
  *(uint4*)&tile[row][cb + 8] = *(const uint4*)(src + 8);
  __syncthreads();
  u16 buf[16];
#pragma unroll
  for (int j = 0; j < 16; ++j) buf[j] = tile[cb + j][row];
  u16* dst = vt + (size_t)(head * 64 + row) * 2048 + t0 + cb;
  *(uint4*)dst = *(const uint4*)&buf[0];
  *(uint4*)(dst + 8) = *(const uint4*)&buf[8];
}

// ---------------- attention phase A (v4 + T5 setprio): QBLK=128, KVBLK=64 ---------
// R13-measured structure; this round adds s_setprio(1) around the QK and PV MFMA
// clusters (T5). Catalog: +4-7% where blocks sit at different phases (m191) — true
// here (LPT blocks run 2..8 iters, 3 blocks/CU); null only for lockstep grids.
__global__ __launch_bounds__(512) void attn_part(const u16* __restrict__ qkv,
                                                 const u16* __restrict__ vt,
                                                 u16* __restrict__ pnum,
                                                 float* __restrict__ pden) {
  const int id = blockIdx.x;
  const int head = id & 15;
  const int rem = id >> 4;                       // [0,40)
  int qb2, c;
  if (rem < 4)       { qb2 = 4 + rem;                          c = 0; }
  else if (rem < 12) { const int t = rem - 4;  qb2 = 8 + (t >> 1);  c = t & 1; }
  else if (rem < 24) { const int t = rem - 12; qb2 = 12 + t / 3;    c = t % 3; }
  else               { const int t = rem - 24; qb2 = ((t & 3) << 2) + 3 - (t >> 2); c = qb2 >> 2; }
  const int a2 = qb2 >> 2, b2 = qb2 & 3;
  const int slot = head * 40 + ((a2 * (a2 + 1)) << 1) + b2 * (a2 + 1) + c;

  __shared__ __align__(16) u16 Ks[2][64 * 64];
  __shared__ __align__(16) u16 Vs[2][64 * 64];  // V^T tiles: [d][s]
  __shared__ __align__(16) u16 QP[8][16 * 64];  // Q staging ALIASED w/ per-wave P scratch
  const int tid = threadIdx.x;
  const int lane = tid & 63;
  const int w = tid >> 6;                        // [0,8)
  const int l15 = lane & 15;
  const int lhi = lane >> 4;
  const int qbase = qb2 << 7;                    // 128 q-rows per block
  const float slope = exp2f(-0.5f * (float)(head + 1));

  auto stageKV = [&](int buf, int s0) {          // 512 chunks each, 1 per thread
    const int row = tid >> 3;
    const int cb = (tid & 7) << 4;
    const int src = cb ^ ((row & 7) << 4);
    async16((char*)Ks[buf] + tid * 16,
            (const char*)qkv + ((size_t)(s0 + row) * 3072 + 1024 + head * 64) * 2 + src);
    async16((char*)Vs[buf] + tid * 16,
            (const char*)vt + ((size_t)(head * 64 + row) * 2048 + s0) * 2 + src);
  };

  const int sfirst = c << 9;
  const int smax = min(qbase + 64, sfirst + 448);  // last KV tile (s0 <= max q row)
#pragma unroll
  for (int p = 0; p < 2; ++p) {                  // stage Q (128 rows, 1024 chunks)
    const int cc = p * 512 + tid;
    const int row = cc >> 3;
    const int cb = (cc & 7) << 4;
    const int src = cb ^ ((row & 7) << 4);
    async16((char*)QP + cc * 16,
            (const char*)qkv + ((size_t)(qbase + row) * 3072 + head * 64) * 2 + src);
  }
  stageKV(0, sfirst);
  __syncthreads();                               // Q + buf0 staged (vmcnt drained)

  bf16x8 qf[2];                                  // wave w reads only its own stripe QP[w]
#pragma unroll
  for (int kk = 0; kk < 2; ++kk) {
    const int row = (w << 4) + l15;
    const int off = row * 128 + (((kk << 6) + (lhi << 4)) ^ ((row & 7) << 4));
    qf[kk] = *(const bf16x8*)((const char*)QP + off);
  }

  f32x4 oacc[4] = {};
  float rs[4] = {0.f, 0.f, 0.f, 0.f};
  u16* pw = (u16*)QP[w];
  int cur = 0;

  for (int s0 = sfirst; s0 <= smax; s0 += 64) {
    if (s0 + 64 <= smax) stageKV(cur ^ 1, s0 + 64);  // issue next-tile loads first
    const char* Kc = (const char*)Ks[cur];
    const char* Vc = (const char*)Vs[cur];

    bf16x8 kf[4][2];                             // phase 1: all K-frag reads
#pragma unroll
    for (int bb = 0; bb < 4; ++bb)
#pragma unroll
      for (int kk = 0; kk < 2; ++kk) {
        const int row = (bb << 4) + l15;
        const int off = row * 128 + (((kk << 6) + (lhi << 4)) ^ ((row & 7) << 4));
        kf[bb][kk] = *(const bf16x8*)(Kc + off);
      }
    f32x4 sa[4];                                 // phase 2: all QK MFMAs (T5 boosted)
    __builtin_amdgcn_s_setprio(1);
#pragma unroll
    for (int bb = 0; bb < 4; ++bb) {
      f32x4 z = {0.f, 0.f, 0.f, 0.f};
      z = MFMA(qf[0], kf[bb][0], z);
      sa[bb] = MFMA(qf[1], kf[bb][1], z);
    }
    __builtin_amdgcn_s_setprio(0);
#pragma unroll
    for (int bb = 0; bb < 4; ++bb) {             // phase 3: p4 + P-writes (16 elems)
      const int s_abs = s0 + (bb << 4) + l15;
#pragma unroll
      for (int r = 0; r < 4; ++r) {
        const int prow = (lhi << 2) + r;
        const int q_abs = qbase + (w << 4) + prow;
        float p4 = 0.f;
        if (s_abs <= q_abs) {                    // masked: ref value ~6e-19, skip
          const float sc = sa[bb][r] * 0.125f - slope * (float)(q_abs - s_abs);
          const float t = rsig_fast(sc);
          const float t2 = t * t;
          p4 = t2 * t2;
        }
        rs[r] += p4;
        const int pcol2 = ((bb << 4) + l15) << 1;
        const int poff = prow * 128 + (pcol2 ^ ((prow & 7) << 4));
        *(u16*)((char*)pw + poff) = f2bf(p4);    // D-layout -> swizzled LDS
      }
    }
    bf16x8 pf[2];                                // phase 4: reload P in A-layout
#pragma unroll
    for (int kk = 0; kk < 2; ++kk) {
      const int row = l15;
      const int off = row * 128 + (((kk << 6) + (lhi << 4)) ^ ((row & 7) << 4));
      pf[kk] = *(const bf16x8*)((const char*)pw + off);
    }
    __builtin_amdgcn_s_setprio(1);               // phase 5: PV (T5 boosted)
#pragma unroll
    for (int db = 0; db < 4; ++db) {
#pragma unroll
      for (int kk = 0; kk < 2; ++kk) {
        const int row = (db << 4) + l15;         // row of V^T = d
        const int off = row * 128 + (((kk << 6) + (lhi << 4)) ^ ((row & 7) << 4));
        const bf16x8 vf = *(const bf16x8*)(Vc + off);
        oacc[db] = MFMA(pf[kk], vf, oacc[db]);
      }
    }
    __builtin_amdgcn_s_setprio(0);
    __syncthreads();                             // next buf staged + all reads done
    cur ^= 1;
  }

#pragma unroll
  for (int r = 0; r < 4; ++r) {                  // row-sum of p4 over the 16-lane group
    float v = rs[r];
    v += __shfl_xor(v, 1);
    v += __shfl_xor(v, 2);
    v += __shfl_xor(v, 4);
    v += __shfl_xor(v, 8);
    rs[r] = v;
  }
  if (l15 == 0) {                                // one writer per q-row (128 rows)
#pragma unroll
    for (int r = 0; r < 4; ++r)
      pden[(size_t)slot * 128 + (w << 4) + (lhi << 2) + r] = rs[r];
  }
  __syncthreads();
#pragma unroll
  for (int db = 0; db < 4; ++db)                 // pack partial num into LDS (linear)
#pragma unroll
    for (int r = 0; r < 4; ++r)
      pw[((lhi << 2) + r) * 64 + (db << 4) + l15] = f2bf(oacc[db][r]);
  __syncthreads();
  {                                              // coalesced 16B stores of num
    const int row = lane >> 2;
    const int cb = (lane & 3) << 4;
    const u16* s = pw + row * 64 + cb;
    const uint4 d0 = *(const uint4*)s;
    const uint4 d1 = *(const uint4*)(s + 8);
    u16* dst = pnum + (size_t)slot * 8192 + ((w << 4) + row) * 64 + cb;
    *(uint4*)dst = d0;
    *(uint4*)(dst + 8) = d1;
  }
}

// ---------------- attention phase B: merge partials, divide, write ATTN -----------
// Block = one (head, 64-row q-tile); maps into its 128-row slot group (qb2 = qb>>1).
__global__ __launch_bounds__(256) void attn_merge(const u16* __restrict__ pnum,
                                                  const float* __restrict__ pden,
                                                  u16* __restrict__ out) {
  const int head = blockIdx.x >> 5;
  const int qb = blockIdx.x & 31;
  const int qb2 = qb >> 1;
  const int a2 = qb >> 3;                        // == qb2>>2
  const int nc = a2 + 1;
  const int slot0 = head * 40 + ((a2 * (a2 + 1)) << 1) + (qb2 & 3) * (a2 + 1);
  const int tid = threadIdx.x;
  const int row = tid >> 2;
  const int c0 = (tid & 3) << 4;
  const int rr = ((qb & 1) << 6) + row;          // row within 128-row slot

  float acc[16] = {};
  float den = 0.f;
  for (int ci = 0; ci < nc; ++ci) {
    const int slot = slot0 + ci;
    den += pden[(size_t)slot * 128 + rr];
    const u16* np = pnum + (size_t)slot * 8192 + rr * 64 + c0;
    const uint4 n0 = *(const uint4*)np;
    const uint4 n1 = *(const uint4*)(np + 8);
    const u16* ns0 = (const u16*)&n0;
    const u16* ns1 = (const u16*)&n1;
#pragma unroll
    for (int j = 0; j < 8; ++j) {
      acc[j] += bf2f(ns0[j]);
      acc[8 + j] += bf2f(ns1[j]);
    }
  }
  const float inv = 1.f / (den + 1e-6f);
  u16 ob[16];
#pragma unroll
  for (int j = 0; j < 16; ++j) ob[j] = f2bf(acc[j] * inv);
  u16* dst = out + (size_t)((qb << 6) + row) * 1024 + head * 64 + c0;
  *(uint4*)dst = *(const uint4*)&ob[0];
  *(uint4*)(dst + 8) = *(const uint4*)&ob[8];
}

// ------------------------------- launcher ----------------------------------------
extern "C" void kernel_launch(void* const* d_in, const int* in_sizes, int n_in,
                              void* d_out, int out_size, void* d_ws, size_t ws_size,
                              hipStream_t stream) {
  const float* x     = (const float*)d_in[0];
  const float* wqkv  = (const float*)d_in[1];
  const float* wout  = (const float*)d_in[2];
  const float* wmer  = (const float*)d_in[3];
  const float* w3    = (const float*)d_in[4];
  const float* n1w   = (const float*)d_in[5];
  const float* n2w   = (const float*)d_in[6];
  char* ws = (char*)d_ws;

  // workspace layout (bytes), total 79,691,776 — byte-identical to R13.
  u16*   WQKV = (u16*)(ws + 0);            // [3072][1024] bf16, 6MB   conv->qkvgemm
  u16*   WOUT = (u16*)(ws + 6291456);      // [1024][1024], 2MB        conv->woutgemm
  u16*   WMER = (u16*)(ws + 8388608);      // [8192][1024], 16MB       conv->ffn1
  u16*   W3B  = (u16*)(ws + 25165824);     // [1024][4096], 8MB        conv->w3gemm
  u16*   H    = (u16*)(ws + 33554432);     // [2048][1024], 4MB        mrnorm1->qkvgemm
  u16*   QKV  = (u16*)(ws + 37748736);     // [2048][3072], 12MB       qkvgemm->attn (direct)
  u16*   VT   = (u16*)(ws + 50331648);     // [1024][2048], 4MB        transpose->attn
  u16*   PNUM = (u16*)(ws + 54525952);     // [640][128][64] bf16, 10MB attn_part->merge
  float* PDEN = (float*)(ws + 65011712);   // [640][128] fp32, 0.33MB
  u16*   ATTN = (u16*)(ws + 65536000);     // [2048][1024], 4MB        merge->woutgemm
  u16*   WOP  = (u16*)(ws + 37748736);     // [4][2048][1024], 16MB    (aliases dead QKV+VT)
  float* X1   = (float*)(ws + 54525952);   // [2048][1024] fp32, 8MB   (aliases dead PNUM)
  u16*   H2   = (u16*)(ws + 33554432);     // 4MB (aliases dead H)     fused norm->ffn1
  u16*   HID  = (u16*)(ws + 37748736);     // [2048][4096], 16MB (aliases dead WOP)
  u16*   W3P  = (u16*)(ws + 62914560);     // [4][2048][1024], 16MB (aliases dead ATTN) ->79691776

  to_bf16_all<<<8192, 256, 0, stream>>>(wqkv, WQKV, wout, WOUT, wmer, WMER, w3, W3B);

  mrnorm<<<2048, 256, 0, stream>>>(x, n1w, H);
  // QKV GEMM direct, 128x128 tile (R13-measured best; R17's 64x128 reshape was neutral)
  gemm_bt<0, true><<<16 * 24, 256, 0, stream>>>(H, 1024, WQKV, 1024, QKV, nullptr,
                                                2048, 3072, 1024);
  transpose_v<<<512, 256, 0, stream>>>(QKV, VT);
  // attn v4 + T5 setprio: QBLK=128, KVBLK=64; 640 blocks, LPT-ordered
  attn_part<<<640, 512, 0, stream>>>(QKV, VT, PNUM, PDEN);
  attn_merge<<<512, 256, 0, stream>>>(PNUM, PDEN, ATTN);
  // wout split-K=4 -> partials, then FUSED reduce+mrnorm2: X1 = x + sum, H2 = norm
  gemm_bt<0, true><<<dim3(16 * 8, 4), 256, 0, stream>>>(ATTN, 1024, WOUT, 1024, WOP,
                                                        nullptr, 2048, 1024, 256);
  wout_reduce_norm<<<2048, 256, 0, stream>>>(WOP, x, n2w, X1, H2);

  // fused FFN1 v2: 1024 blocks, dbuf, 128x64 gate + 128x64 val per block
  gemm_ffn1<<<1024, 256, 0, stream>>>(H2, WMER, HID);
  // w3 split-K=4: 512 blocks, 16 K-steps/chunk; reduce adds resid X1 -> out.
  gemm_bt<0, true><<<dim3(16 * 8, 4), 256, 0, stream>>>(HID, 4096, W3B, 4096, W3P,
                                                        nullptr, 2048, 1024, 1024);
  splitk_reduce<4, false><<<1024, 256, 0, stream>>>(W3P, 2097152, X1, (float*)d_out);
}